// Round 3
// baseline (16971.428 us; speedup 1.0000x reference)
//
#include <hip/hip_runtime.h>

#define NH 1024
#define NV 31
#define TT 512
#define BB 2048

typedef short short8 __attribute__((ext_vector_type(8)));
typedef float floatx16 __attribute__((ext_vector_type(16)));
typedef _Float16 half8 __attribute__((ext_vector_type(8)));
typedef unsigned short ushort_t;

__device__ inline unsigned short f2bf(float f) {
    unsigned int u = __builtin_bit_cast(unsigned int, f);
    unsigned int r = u + 0x7FFFu + ((u >> 16) & 1u);
    return (unsigned short)(r >> 16);
}
__device__ inline float bf2f(unsigned short s) {
    unsigned int u = ((unsigned int)s) << 16;
    return __builtin_bit_cast(float, u);
}
__device__ inline float load_amb(const void* p, int i, bool isbf) {
    return isbf ? bf2f(((const unsigned short*)p)[i]) : ((const float*)p)[i];
}

// ---------------- init: convert params; W -> MFMA fragment-chunk order ------
// Chunk layout (A, W, h): chunk c = grp*64 + kg holds a 32x16 tile:
//   elem (lane, j) = M[grp*32 + (lane&31)][kg*16 + ((lane>>5)<<3) + j]
// at linear index c*512 + lane*8 + j  -> a wave's fragment load is one
// fully-coalesced 1 KiB global_load (16B/lane, contiguous).
// WhoH: f16 chunk layout of Who padded to 32 rows (single 32-row group).
__global__ void k_convert(const void* emb, const void* Whh, const void* bhh,
                          const void* Who, const void* bho, const void* gam,
                          const void* bet,
                          ushort_t* __restrict__ Wbf, float* __restrict__ embF,
                          ushort_t* __restrict__ WhoH, float* __restrict__ bhhF,
                          float* __restrict__ gamF, float* __restrict__ betF,
                          float* __restrict__ bhoF) {
    bool isbf = (((const unsigned int*)gam)[0] != 0x3F800000u);
    int i = blockIdx.x * 256 + threadIdx.x;
    if (i < NH * NH) {
        int j = i & 7, lam = (i >> 3) & 63, chunk = i >> 9;
        int cg = chunk >> 6, kg = chunk & 63;
        int n = cg * 32 + (lam & 31);
        int k = kg * 16 + ((lam >> 5) << 3) + j;
        int src = n * NH + k;
        Wbf[i] = isbf ? ((const unsigned short*)Whh)[src]
                      : f2bf(((const float*)Whh)[src]);
    }
    if (i < NV * NH) embF[i] = load_amb(emb, i, isbf);
    if (i < 32 * NH) {  // Who -> f16 chunks, rows padded 31->32
        int j = i & 7, lam = (i >> 3) & 63, kg = i >> 9;
        int v = lam & 31;
        int k = kg * 16 + ((lam >> 5) << 3) + j;
        float w = (v < NV) ? load_amb(Who, v * NH + k, isbf) : 0.f;
        WhoH[i] = __builtin_bit_cast(ushort_t, (_Float16)w);
    }
    if (i < NH) {
        bhhF[i] = load_amb(bhh, i, isbf);
        gamF[i] = load_amb(gam, i, isbf);
        betF[i] = load_amb(bet, i, isbf);
    }
    if (i < NV) bhoF[i] = load_amb(bho, i, isbf);
}

// A_0 = bf16(emb[x[:,0]]) written in fragment-chunk order (h0 == 0)
__global__ void k_initA(const int* __restrict__ x, const float* __restrict__ embF,
                        ushort_t* __restrict__ Abf) {
    int i = blockIdx.x * 256 + threadIdx.x;
    if (i >= BB * NH) return;
    int j = i & 7, lam = (i >> 3) & 63, chunk = i >> 9;
    int rg = chunk >> 6, kg = chunk & 63;
    int row = rg * 32 + (lam & 31);
    int k = kg * 16 + ((lam >> 5) << 3) + j;
    int xi = x[row * TT];
    Abf[i] = f2bf(embF[xi * NH + k]);
}

// xT[t][row] = x[row][t]  (coalesced writes; reads L2-cached line-reuse)
__global__ void k_xT(const int* __restrict__ x, int* __restrict__ xT) {
    int i = blockIdx.x * 256 + threadIdx.x;
    if (i >= BB * TT) return;
    int t = i >> 11, row = i & (BB - 1);
    xT[i] = x[row * TT + t];
}

// ---------------- fused per-step kernel -------------------------------------
// 256 blocks x 256 threads, role-split:
//   id <  128: GEMM block. Tile 128x128, 4 waves as 2x2 of 64x64 wave tiles
//              (4 loads : 4 MFMAs = 1 KiB/MFMA). Epilogue: bias/relu/stats,
//              LDS bounce -> chunk-order emission of h(t) and A(t+1).
//   id < 192:  P1+P2 block (runs CONCURRENTLY with GEMM blocks; projection of
//              step t-1 is independent of step t's GEMM). BN coefs, then the
//              32-row group g's output projection with the K-loop split over
//              4 waves (16 iters each) + LDS reduce. Also zeroes aNext.
//   id >= 192: exit (keeps per-CU load balanced at <=1 heavy block).
__global__ __launch_bounds__(256) void k_step(
        int t, const int* __restrict__ xT,
        const ushort_t* __restrict__ Acur, ushort_t* __restrict__ Anext,
        const ushort_t* __restrict__ Wbf, const float* __restrict__ bhhF,
        const float* __restrict__ gamF, const float* __restrict__ betF,
        const float* __restrict__ embF, const ushort_t* __restrict__ WhoH,
        const float* __restrict__ bhoF,
        const float* __restrict__ aPrev, float* __restrict__ aCur,
        float* __restrict__ aNext,
        ushort_t* __restrict__ hbCur, const ushort_t* __restrict__ hbPrev,
        float* __restrict__ out) {
    __shared__ __align__(16) char smem[69632];
    int tid = threadIdx.x;
    int lane = tid & 63, wave = tid >> 6;
    int l31 = lane & 31, l5 = lane >> 5;
    int id = blockIdx.x;

    if (id < 128) {
        if (t >= TT) return;
        int bx = id & 15, by = id >> 4;
        int wr = wave >> 1, wc = wave & 1;
        ushort_t (*ldsH)[136] = (ushort_t(*)[136])smem;
        ushort_t (*ldsA)[136] = (ushort_t(*)[136])(smem + 34816);

        const ushort_t* Ap = Acur + (size_t)(4 * bx + 2 * wr) * 64 * 512 + lane * 8;
        const ushort_t* Bp = Wbf + (size_t)(4 * by + 2 * wc) * 64 * 512 + lane * 8;
        floatx16 acc00 = (floatx16)0.f, acc01 = (floatx16)0.f;
        floatx16 acc10 = (floatx16)0.f, acc11 = (floatx16)0.f;
#pragma unroll 4
        for (int kg = 0; kg < 64; kg++) {
            short8 a0 = *(const short8*)(Ap + kg * 512);
            short8 a1 = *(const short8*)(Ap + 64 * 512 + kg * 512);
            short8 b0 = *(const short8*)(Bp + kg * 512);
            short8 b1 = *(const short8*)(Bp + 64 * 512 + kg * 512);
            acc00 = __builtin_amdgcn_mfma_f32_32x32x16_bf16(a0, b0, acc00, 0, 0, 0);
            acc01 = __builtin_amdgcn_mfma_f32_32x32x16_bf16(a0, b1, acc01, 0, 0, 0);
            acc10 = __builtin_amdgcn_mfma_f32_32x32x16_bf16(a1, b0, acc10, 0, 0, 0);
            acc11 = __builtin_amdgcn_mfma_f32_32x32x16_bf16(a1, b1, acc11, 0, 0, 0);
        }
        int rbase = 128 * bx + 64 * wr;
        int xoff = (t + 1) * BB;
        auto epi = [&](floatx16 aR0, floatx16 aR1, int ci) {
            int col = 128 * by + 64 * wc + 32 * ci + l31;
            float bias = bhhF[col];
            float sv = 0.f, qv = 0.f;
#pragma unroll
            for (int r = 0; r < 16; r++) {
                int rl = (r & 3) + 8 * (r >> 2) + 4 * l5;
                float v = aR0[r] + bias;
                v = v > 0.f ? v : 0.f;
                sv += v; qv += v * v;
                ldsH[64 * wr + rl][64 * wc + 32 * ci + l31] = f2bf(v);
                if (t < TT - 1) {
                    int xi = xT[xoff + rbase + rl];
                    ldsA[64 * wr + rl][64 * wc + 32 * ci + l31] =
                        f2bf(v + embF[xi * NH + col]);
                }
            }
#pragma unroll
            for (int r = 0; r < 16; r++) {
                int rl = 32 + (r & 3) + 8 * (r >> 2) + 4 * l5;
                float v = aR1[r] + bias;
                v = v > 0.f ? v : 0.f;
                sv += v; qv += v * v;
                ldsH[64 * wr + rl][64 * wc + 32 * ci + l31] = f2bf(v);
                if (t < TT - 1) {
                    int xi = xT[xoff + rbase + rl];
                    ldsA[64 * wr + rl][64 * wc + 32 * ci + l31] =
                        f2bf(v + embF[xi * NH + col]);
                }
            }
            sv += __shfl_xor(sv, 32); qv += __shfl_xor(qv, 32);
            if (lane < 32) {
                atomicAdd(&aCur[col], sv);
                atomicAdd(&aCur[NH + col], qv);
            }
        };
        epi(acc00, acc10, 0);
        epi(acc01, acc11, 1);
        __syncthreads();
        // chunk-order emission: 32 chunks/block, 8 per wave
#pragma unroll
        for (int c = 0; c < 8; c++) {
            int cc = wave * 8 + c, rg = cc >> 3, kg = cc & 7;
            size_t dst = (size_t)((4 * bx + rg) * 64 + 8 * by + kg) * 512 + lane * 8;
            short8 hv = *(const short8*)&ldsH[rg * 32 + l31][kg * 16 + (l5 << 3)];
            *(short8*)(hbCur + dst) = hv;
            if (t < TT - 1) {
                short8 av = *(const short8*)&ldsA[rg * 32 + l31][kg * 16 + (l5 << 3)];
                *(short8*)(Anext + dst) = av;
            }
        }
    } else if (id < 192) {
        int g = id - 128;
        if (g < 32 && tid < 64) aNext[g * 64 + tid] = 0.f;
        if (t == 0) return;
        float* rgL = (float*)smem;
        float* bbL = rgL + 1024;
        float* red = (float*)(smem + 8192);  // [4][64][17] floats
        // P1: BN coefficients
#pragma unroll
        for (int m = 0; m < 4; m++) {
            int f = tid + m * 256;
            float mu = aPrev[f] * (1.0f / BB);
            float var = aPrev[f + NH] * (1.0f / BB) - mu * mu;
            float rg_ = rsqrtf(var + 1e-5f) * gamF[f];
            rgL[f] = rg_;
            bbL[f] = betF[f] - mu * rg_;
        }
        __syncthreads();
        // P2: wave-split K (16 chunks each)
        const ushort_t* Hp = hbPrev + (size_t)g * 64 * 512 + lane * 8;
        const _Float16* Wh = (const _Float16*)WhoH;
        int kbase = l5 << 3;
        floatx16 acc = (floatx16)0.f;
#pragma unroll 4
        for (int kk = 0; kk < 16; kk++) {
            int kg = wave * 16 + kk;
            short8 hb8 = *(const short8*)(Hp + kg * 512);
            int k0 = kg * 16 + kbase;
            float rgv[8], bbv[8];
            *(float4*)&rgv[0] = *(const float4*)&rgL[k0];
            *(float4*)&rgv[4] = *(const float4*)&rgL[k0 + 4];
            *(float4*)&bbv[0] = *(const float4*)&bbL[k0];
            *(float4*)&bbv[4] = *(const float4*)&bbL[k0 + 4];
            half8 a;
#pragma unroll
            for (int j = 0; j < 8; j++) {
                float hv = bf2f((ushort_t)hb8[j]);
                a[j] = (_Float16)(hv * rgv[j] + bbv[j]);
            }
            half8 b = *(const half8*)(Wh + kg * 512 + lane * 8);
            acc = __builtin_amdgcn_mfma_f32_32x32x16_f16(a, b, acc, 0, 0, 0);
        }
        float* myred = red + (wave * 64 + lane) * 17;
#pragma unroll
        for (int j = 0; j < 16; j++) myred[j] = acc[j];
        __syncthreads();
        if (wave == 0) {
            float bo = (l31 < NV) ? bhoF[l31] : 0.f;
#pragma unroll
            for (int r = 0; r < 16; r++) {
                float s = red[(0 * 64 + lane) * 17 + r] +
                          red[(1 * 64 + lane) * 17 + r] +
                          red[(2 * 64 + lane) * 17 + r] +
                          red[(3 * 64 + lane) * 17 + r];
                int row = g * 32 + (r & 3) + 8 * (r >> 2) + 4 * l5;
                if (l31 < NV)
                    out[(size_t)row * (TT * NV) + (size_t)(t - 1) * NV + l31] =
                        s + bo;
            }
        }
    }
    // id >= 192: immediate exit
}

extern "C" void kernel_launch(void* const* d_in, const int* in_sizes, int n_in,
                              void* d_out, int out_size, void* d_ws,
                              size_t ws_size, hipStream_t stream) {
    const int* x = (const int*)d_in[0];
    const void* emb = d_in[1];
    const void* Whh = d_in[2];
    const void* bhh = d_in[3];
    const void* Who = d_in[4];
    const void* bho = d_in[5];
    const void* gam = d_in[6];
    const void* bet = d_in[7];

    char* ws = (char*)d_ws;
    ushort_t* Abf = (ushort_t*)(ws);                 // 2 x 4 MiB (chunk order)
    ushort_t* hbf = (ushort_t*)(ws + (8u << 20));    // 2 x 4 MiB (chunk order)
    ushort_t* Wbf = (ushort_t*)(ws + (16u << 20));   // 2 MiB (chunk order)
    float* embF = (float*)(ws + (18u << 20));        // 124 KiB (128 slot)
    ushort_t* WhoH = (ushort_t*)(ws + (18u << 20) + (128u << 10));  // 64 KiB
    float* bhhF = (float*)(ws + (18u << 20) + (192u << 10));
    float* gamF = bhhF + 1024;
    float* betF = gamF + 1024;
    float* bhoF = betF + 1024;
    float* acc3 = bhoF + 1024;  // 3 x [S(1024) | Q(1024)] = 24 KiB
    int* xT = (int*)(ws + (19u << 20));              // 4 MiB
    float* out = (float*)d_out;

    hipMemsetAsync(acc3, 0, 3 * 2 * NH * sizeof(float), stream);
    k_convert<<<(NH * NH + 255) / 256, 256, 0, stream>>>(
        emb, Whh, bhh, Who, bho, gam, bet, Wbf, embF, WhoH, bhhF, gamF, betF,
        bhoF);
    k_initA<<<(BB * NH + 255) / 256, 256, 0, stream>>>(x, embF, Abf);
    k_xT<<<(BB * TT + 255) / 256, 256, 0, stream>>>(x, xT);

    for (int t = 0; t <= TT; t++) {
        const ushort_t* Acur = Abf + (size_t)(t & 1) * BB * NH;
        ushort_t* Anext = Abf + (size_t)((t + 1) & 1) * BB * NH;
        ushort_t* hbCur = hbf + (size_t)(t & 1) * BB * NH;
        const ushort_t* hbPrev = hbf + (size_t)((t + 1) & 1) * BB * NH;
        const float* aPrev = acc3 + ((t + 2) % 3) * 2 * NH;
        float* aCur = acc3 + (t % 3) * 2 * NH;
        float* aNext = acc3 + ((t + 1) % 3) * 2 * NH;
        k_step<<<dim3(256), 256, 0, stream>>>(
            t, xT, Acur, Anext, Wbf, bhhF, gamF, betF, embF, WhoH, bhoF, aPrev,
            aCur, aNext, hbCur, hbPrev, out);
    }
}

// Round 4
// 8815.927 us; speedup vs baseline: 1.9251x; 1.9251x over previous
//
#include <hip/hip_runtime.h>

#define NH 1024
#define NV 31
#define TT 512
#define BB 2048

typedef short short8 __attribute__((ext_vector_type(8)));
typedef float floatx16 __attribute__((ext_vector_type(16)));
typedef _Float16 half8 __attribute__((ext_vector_type(8)));
typedef unsigned short ushort_t;

__device__ inline unsigned short f2bf(float f) {
    unsigned int u = __builtin_bit_cast(unsigned int, f);
    unsigned int r = u + 0x7FFFu + ((u >> 16) & 1u);
    return (unsigned short)(r >> 16);
}
__device__ inline float bf2f(unsigned short s) {
    unsigned int u = ((unsigned int)s) << 16;
    return __builtin_bit_cast(float, u);
}
__device__ inline float load_amb(const void* p, int i, bool isbf) {
    return isbf ? bf2f(((const unsigned short*)p)[i]) : ((const float*)p)[i];
}

// async global->LDS, 16B per lane; LDS dest is wave-uniform base + lane*16
__device__ inline void gl_lds16(const ushort_t* g, ushort_t* l) {
    __builtin_amdgcn_global_load_lds(
        (const __attribute__((address_space(1))) unsigned int*)g,
        (__attribute__((address_space(3))) unsigned int*)l, 16, 0, 0);
}

// ---------------- init: convert params; W -> MFMA fragment-chunk order ------
// Chunk layout (A, W, h): chunk c = grp*64 + kg holds a 32x16 tile:
//   elem (lane, j) = M[grp*32 + (lane&31)][kg*16 + ((lane>>5)<<3) + j]
// at linear index c*512 + lane*8 + j  -> one coalesced 1 KiB load per chunk.
__global__ void k_convert(const void* emb, const void* Whh, const void* bhh,
                          const void* Who, const void* bho, const void* gam,
                          const void* bet,
                          ushort_t* __restrict__ Wbf, float* __restrict__ embF,
                          ushort_t* __restrict__ WhoH, float* __restrict__ bhhF,
                          float* __restrict__ gamF, float* __restrict__ betF,
                          float* __restrict__ bhoF) {
    bool isbf = (((const unsigned int*)gam)[0] != 0x3F800000u);
    int i = blockIdx.x * 256 + threadIdx.x;
    if (i < NH * NH) {
        int j = i & 7, lam = (i >> 3) & 63, chunk = i >> 9;
        int cg = chunk >> 6, kg = chunk & 63;
        int n = cg * 32 + (lam & 31);
        int k = kg * 16 + ((lam >> 5) << 3) + j;
        int src = n * NH + k;
        Wbf[i] = isbf ? ((const unsigned short*)Whh)[src]
                      : f2bf(((const float*)Whh)[src]);
    }
    if (i < NV * NH) embF[i] = load_amb(emb, i, isbf);
    if (i < 32 * NH) {  // Who -> f16 chunks, rows padded 31->32
        int j = i & 7, lam = (i >> 3) & 63, kg = i >> 9;
        int v = lam & 31;
        int k = kg * 16 + ((lam >> 5) << 3) + j;
        float w = (v < NV) ? load_amb(Who, v * NH + k, isbf) : 0.f;
        WhoH[i] = __builtin_bit_cast(ushort_t, (_Float16)w);
    }
    if (i < NH) {
        bhhF[i] = load_amb(bhh, i, isbf);
        gamF[i] = load_amb(gam, i, isbf);
        betF[i] = load_amb(bet, i, isbf);
    }
    if (i < NV) bhoF[i] = load_amb(bho, i, isbf);
}

// A_0 = bf16(emb[x[:,0]]) written in fragment-chunk order (h0 == 0)
__global__ void k_initA(const int* __restrict__ x, const float* __restrict__ embF,
                        ushort_t* __restrict__ Abf) {
    int i = blockIdx.x * 256 + threadIdx.x;
    if (i >= BB * NH) return;
    int j = i & 7, lam = (i >> 3) & 63, chunk = i >> 9;
    int rg = chunk >> 6, kg = chunk & 63;
    int row = rg * 32 + (lam & 31);
    int k = kg * 16 + ((lam >> 5) << 3) + j;
    int xi = x[row * TT];
    Abf[i] = f2bf(embF[xi * NH + k]);
}

// xT[t][row] = x[row][t]
__global__ void k_xT(const int* __restrict__ x, int* __restrict__ xT) {
    int i = blockIdx.x * 256 + threadIdx.x;
    if (i >= BB * TT) return;
    int t = i >> 11, row = i & (BB - 1);
    xT[i] = x[row * TT + t];
}

// ---------------- fused per-step kernel -------------------------------------
// 256 blocks x 512 threads. Block tile 64 rows x 128 cols; 8 waves as 2x4 of
// 32x32 tiles. GEMM operands double-buffered via global_load_lds (8 chunks of
// K per stage, one __syncthreads per stage: its vmcnt(0) drain is the wait).
// XCD-swizzled block ids keep each XCD's working set (2 MiB) L2-resident.
// P2 (blocks id<64): output projection of step t-1, K split over 8 waves +
// LDS reduce. P1 (BN coefs) only in those blocks.
__global__ __launch_bounds__(512) void k_step(
        int t, const int* __restrict__ xT,
        const ushort_t* __restrict__ Acur, ushort_t* __restrict__ Anext,
        const ushort_t* __restrict__ Wbf, const float* __restrict__ bhhF,
        const float* __restrict__ gamF, const float* __restrict__ betF,
        const float* __restrict__ embF, const ushort_t* __restrict__ WhoH,
        const float* __restrict__ bhoF,
        const float* __restrict__ aPrev, float* __restrict__ aCur,
        float* __restrict__ aNext,
        ushort_t* __restrict__ hbCur, const ushort_t* __restrict__ hbPrev,
        float* __restrict__ out) {
    __shared__ __align__(16) char smem[141312];
    ushort_t (*sA)[512] = (ushort_t(*)[512])smem;                    // [32][512]
    ushort_t (*sB)[512] = (ushort_t(*)[512])(smem + 32768);          // [64][512]
    ushort_t (*ldsH)[136] = (ushort_t(*)[136])(smem + 98304);
    ushort_t (*ldsA2)[136] = (ushort_t(*)[136])(smem + 115712);
    float* rgbb = (float*)(smem + 133120);                           // 2048 f
    int tid = threadIdx.x;
    int lane = tid & 63, wave = tid >> 6;
    int l31 = lane & 31, l5 = lane >> 5;
    int id = blockIdx.x;
    // XCD-aware swizzle: XCD (id&7) owns an 8(bx) x 4(by) rectangle
    int rh = (id & 7) >> 1, rv = id & 1;
    int q = id >> 3;
    int bx = rh * 8 + (q & 7), by = rv * 4 + (q >> 3);
    int wr = wave >> 2, wc = wave & 3;

    // issue stage 0 before P1/zeroing so loads fly under them
    if (t < TT) {
#pragma unroll
        for (int c6 = 0; c6 < 6; c6++) {
            int c = wave * 6 + c6;
            if (c < 16) {
                int rg = c >> 3, k = c & 7;
                gl_lds16(Acur + (((size_t)((2 * bx + rg) * 64 + k)) << 9) + lane * 8,
                         &sA[rg * 8 + k][0]);
            } else {
                int cb = c - 16, cg = cb >> 3, k = cb & 7;
                gl_lds16(Wbf + (((size_t)((4 * by + cg) * 64 + k)) << 9) + lane * 8,
                         &sB[cg * 8 + k][0]);
            }
        }
    }
    if (t > 0 && id < 64) {  // P1: BN coefficients (only projection blocks)
#pragma unroll
        for (int m = 0; m < 2; m++) {
            int f = tid + m * 512;
            float mu = aPrev[f] * (1.0f / BB);
            float var = aPrev[f + NH] * (1.0f / BB) - mu * mu;
            float rg_ = rsqrtf(var + 1e-5f) * gamF[f];
            rgbb[f] = rg_;
            rgbb[1024 + f] = betF[f] - mu * rg_;
        }
    }
    if (tid < 128) aNext[by * 128 + tid] = 0.f;
    else if (tid < 256) aNext[NH + by * 128 + tid - 128] = 0.f;
    __syncthreads();  // vmcnt(0) drain: stage 0 landed; P1 visible

    if (t < TT) {
        floatx16 accE = (floatx16)0.f, accO = (floatx16)0.f;
        for (int s = 0; s < 8; s++) {
            int buf = (s & 1) ? 16 : 0;
            if (s < 7) {
                int nb = ((s + 1) & 1) ? 16 : 0;
#pragma unroll
                for (int c6 = 0; c6 < 6; c6++) {
                    int c = wave * 6 + c6;
                    if (c < 16) {
                        int rg = c >> 3, k = c & 7;
                        gl_lds16(Acur + (((size_t)((2 * bx + rg) * 64 + (s + 1) * 8 + k)) << 9) + lane * 8,
                                 &sA[nb + rg * 8 + k][0]);
                    } else {
                        int cb = c - 16, cg = cb >> 3, k = cb & 7;
                        gl_lds16(Wbf + (((size_t)((4 * by + cg) * 64 + (s + 1) * 8 + k)) << 9) + lane * 8,
                                 &sB[nb * 2 + cg * 8 + k][0]);
                    }
                }
            }
#pragma unroll
            for (int k = 0; k < 8; k += 2) {
                short8 a0 = *(const short8*)&sA[buf + wr * 8 + k][lane * 8];
                short8 b0 = *(const short8*)&sB[buf * 2 + wc * 8 + k][lane * 8];
                short8 a1 = *(const short8*)&sA[buf + wr * 8 + k + 1][lane * 8];
                short8 b1 = *(const short8*)&sB[buf * 2 + wc * 8 + k + 1][lane * 8];
                accE = __builtin_amdgcn_mfma_f32_32x32x16_bf16(a0, b0, accE, 0, 0, 0);
                accO = __builtin_amdgcn_mfma_f32_32x32x16_bf16(a1, b1, accO, 0, 0, 0);
            }
            if (s < 7) __syncthreads();  // next stage landed; buf free
        }
        // epilogue: bias+relu, stats, LDS bounces
        int col = by * 128 + wc * 32 + l31;
        float bias = bhhF[col];
        float sv = 0.f, qv = 0.f;
        int xoff = (t + 1) * BB;
#pragma unroll
        for (int r = 0; r < 16; r++) {
            int rl = (r & 3) + 8 * (r >> 2) + 4 * l5;
            float v = accE[r] + accO[r] + bias;
            v = v > 0.f ? v : 0.f;
            sv += v; qv += v * v;
            ldsH[wr * 32 + rl][wc * 32 + l31] = f2bf(v);
            if (t < TT - 1) {
                int xi = xT[xoff + bx * 64 + wr * 32 + rl];
                ldsA2[wr * 32 + rl][wc * 32 + l31] = f2bf(v + embF[xi * NH + col]);
            }
        }
        sv += __shfl_xor(sv, 32); qv += __shfl_xor(qv, 32);
        if (lane < 32) {
            atomicAdd(&aCur[col], sv);
            atomicAdd(&aCur[NH + col], qv);
        }
        __syncthreads();
        // chunk-order emission (16 chunks / block)
#pragma unroll
        for (int c = 0; c < 2; c++) {
            int cc = wave * 2 + c, rg = cc >> 3, kg = cc & 7;
            size_t dst = (((size_t)((2 * bx + rg) * 64 + 8 * by + kg)) << 9) + lane * 8;
            short8 hv = *(const short8*)&ldsH[rg * 32 + l31][kg * 16 + (l5 << 3)];
            *(short8*)(hbCur + dst) = hv;
            if (t < TT - 1) {
                short8 av = *(const short8*)&ldsA2[rg * 32 + l31][kg * 16 + (l5 << 3)];
                *(short8*)(Anext + dst) = av;
            }
        }
    }

    // ---- P2: output projection for step t-1, 8-way K-split ----
    if (t > 0 && id < 64) {
        int g = id;  // 32-row group
        const ushort_t* Hp = hbPrev + ((size_t)g << 15) + lane * 8;
        const _Float16* Wh = (const _Float16*)WhoH;
        int kbase = l5 << 3;
        floatx16 acc = (floatx16)0.f;
#pragma unroll
        for (int kk = 0; kk < 8; kk++) {
            int kg = wave * 8 + kk;
            short8 hb8 = *(const short8*)(Hp + kg * 512);
            int k0 = kg * 16 + kbase;
            float rgv[8], bbv[8];
            *(float4*)&rgv[0] = *(const float4*)&rgbb[k0];
            *(float4*)&rgv[4] = *(const float4*)&rgbb[k0 + 4];
            *(float4*)&bbv[0] = *(const float4*)&rgbb[1024 + k0];
            *(float4*)&bbv[4] = *(const float4*)&rgbb[1024 + k0 + 4];
            half8 a;
#pragma unroll
            for (int j = 0; j < 8; j++) {
                float hv = bf2f((ushort_t)hb8[j]);
                a[j] = (_Float16)(hv * rgv[j] + bbv[j]);
            }
            half8 b = *(const half8*)(Wh + kg * 512 + lane * 8);
            acc = __builtin_amdgcn_mfma_f32_32x32x16_f16(a, b, acc, 0, 0, 0);
        }
        // cross-wave reduce in LDS (reuse staging region; GEMM phase is done)
        float* red = (float*)smem;  // [8][64][17]
        float* myred = red + (wave * 64 + lane) * 17;
#pragma unroll
        for (int j = 0; j < 16; j++) myred[j] = acc[j];
        __syncthreads();
#pragma unroll
        for (int oo = 0; oo < 2; oo++) {
            int o = tid + oo * 512;
            int lo = o >> 4, r = o & 15;
            float s = 0.f;
#pragma unroll
            for (int w = 0; w < 8; w++) s += red[(w * 64 + lo) * 17 + r];
            int v = lo & 31;
            if (v < NV) {
                int row = g * 32 + (r & 3) + 8 * (r >> 2) + 4 * (lo >> 5);
                out[(size_t)row * (TT * NV) + (size_t)(t - 1) * NV + v] = s + bhoF[v];
            }
        }
    }
}

extern "C" void kernel_launch(void* const* d_in, const int* in_sizes, int n_in,
                              void* d_out, int out_size, void* d_ws,
                              size_t ws_size, hipStream_t stream) {
    const int* x = (const int*)d_in[0];
    const void* emb = d_in[1];
    const void* Whh = d_in[2];
    const void* bhh = d_in[3];
    const void* Who = d_in[4];
    const void* bho = d_in[5];
    const void* gam = d_in[6];
    const void* bet = d_in[7];

    char* ws = (char*)d_ws;
    ushort_t* Abf = (ushort_t*)(ws);                 // 2 x 4 MiB (chunk order)
    ushort_t* hbf = (ushort_t*)(ws + (8u << 20));    // 2 x 4 MiB (chunk order)
    ushort_t* Wbf = (ushort_t*)(ws + (16u << 20));   // 2 MiB (chunk order)
    float* embF = (float*)(ws + (18u << 20));        // 124 KiB (128 slot)
    ushort_t* WhoH = (ushort_t*)(ws + (18u << 20) + (128u << 10));  // 64 KiB
    float* bhhF = (float*)(ws + (18u << 20) + (192u << 10));
    float* gamF = bhhF + 1024;
    float* betF = gamF + 1024;
    float* bhoF = betF + 1024;
    float* acc3 = bhoF + 1024;  // 3 x [S(1024) | Q(1024)] = 24 KiB
    int* xT = (int*)(ws + (19u << 20));              // 4 MiB
    float* out = (float*)d_out;

    hipMemsetAsync(acc3, 0, 3 * 2 * NH * sizeof(float), stream);
    k_convert<<<(NH * NH + 255) / 256, 256, 0, stream>>>(
        emb, Whh, bhh, Who, bho, gam, bet, Wbf, embF, WhoH, bhhF, gamF, betF,
        bhoF);
    k_initA<<<(BB * NH + 255) / 256, 256, 0, stream>>>(x, embF, Abf);
    k_xT<<<(BB * TT + 255) / 256, 256, 0, stream>>>(x, xT);

    for (int t = 0; t <= TT; t++) {
        const ushort_t* Acur = Abf + (size_t)(t & 1) * BB * NH;
        ushort_t* Anext = Abf + (size_t)((t + 1) & 1) * BB * NH;
        ushort_t* hbCur = hbf + (size_t)(t & 1) * BB * NH;
        const ushort_t* hbPrev = hbf + (size_t)((t + 1) & 1) * BB * NH;
        const float* aPrev = acc3 + ((t + 2) % 3) * 2 * NH;
        float* aCur = acc3 + (t % 3) * 2 * NH;
        float* aNext = acc3 + ((t + 1) % 3) * 2 * NH;
        k_step<<<dim3(256), 512, 0, stream>>>(
            t, xT, Acur, Anext, Wbf, bhhF, gamF, betF, embF, WhoH, bhoF, aPrev,
            aCur, aNext, hbCur, hbPrev, out);
    }
}